// Round 3
// baseline (439.207 us; speedup 1.0000x reference)
//
#include <hip/hip_runtime.h>

// FastAttention (Performer linear attention), MI355X gfx950.  Round 3.
// B=4 L=4096 H=16 D=E=64 M=256, fp32 in/out, bf16 MFMA internally.
//
//   memset ws; k1_kv (barrier-free) -> KVt/Ksum fp32 atomics; k3_out (2 barriers/iter).
// phi(x) = relu((x*D^-0.25) @ P^T) + 1e-3 ; scale folded into P bf16 regs.
// den folded into GEMM4 as an all-columns-equal Ksum B-operand (no LDS reduce).
// R3 fix: wave-private v staging must load 64 floats/lane (16 f4v), not 4.

#define LL 4096
#define HH 16
#define DD 64
#define EE 64
#define MM 256
#define SCALE 0.35355339059327378f  // 64^-0.25

typedef __attribute__((ext_vector_type(8))) __bf16 bf8v;
typedef __attribute__((ext_vector_type(4))) __bf16 bf4v;
typedef __attribute__((ext_vector_type(4))) float f4v;

__device__ __forceinline__ __bf16 f2bf(float f) {
  union { float f; unsigned u; } x; x.f = f;
  unsigned r = (x.u + 0x7FFFu + ((x.u >> 16) & 1u)) >> 16;
  union { unsigned short s; __bf16 b; } y; y.s = (unsigned short)r;
  return y.b;
}

#define MFMA16(a, b, c) __builtin_amdgcn_mfma_f32_16x16x32_bf16(a, b, c, 0, 0, 0)

// ws layout (floats): [ KVt: 64bh * 64e * 256m ][ Ksum: 64bh * 256m ]
#define KV_ELEMS (64 * 64 * 256)
#define KSUM_OFF KV_ELEMS
#define WS_ZERO_BYTES ((size_t)(KV_ELEMS + 64 * 256) * 4)

// ---------------------------------------------------------------------------
// Kernel 1: KVt[bh][e][m] += phi(k)^T v ; Ksum[bh][m].  ZERO barriers.
// grid (8, 64), 256 thr. Block: 512 rows, 8 iters of 64. Wave owns m-band.
// k A-frags: direct global (fragment-order). v: wave-private LDS staging.
// ---------------------------------------------------------------------------
__global__ __launch_bounds__(256, 2)
void k1_kv(const float* __restrict__ kin, const float* __restrict__ vin,
           const float* __restrict__ pin, float* __restrict__ ws) {
  __shared__ __bf16 vt[4 * 64 * 68];   // wave-private v tiles [l][e]
  __shared__ __bf16 kft[4 * 64 * 72];  // wave-private phi(k)^T [m_band][l]

  const int tid = threadIdx.x;
  const int wave = tid >> 6;
  const int lane = tid & 63;
  const int qd = lane >> 4;
  const int nn = lane & 15;
  const int bh = blockIdx.y;
  const int b = bh >> 4, h = bh & 15;
  const int l0 = blockIdx.x * 512;

  __bf16* vtw = vt + wave * (64 * 68);
  __bf16* kftw = kft + wave * (64 * 72);

  // P fragments (B-op of GEMM1): rows m = 64*wave + mt*16 + nn, k d = c*32+qd*8+j.
  bf8v pf[4][2];
#pragma unroll
  for (int mt = 0; mt < 4; ++mt) {
    const float* pr = pin + (size_t)(64 * wave + mt * 16 + nn) * DD;
#pragma unroll
    for (int c = 0; c < 2; ++c) {
      bf8v t;
#pragma unroll
      for (int j = 0; j < 8; ++j) t[j] = f2bf(pr[c * 32 + qd * 8 + j] * SCALE);
      pf[mt][c] = t;
    }
  }

  f4v acc[4][4];  // [mt][et]: rows m = 64w+mt*16+4qd+r, cols e = et*16+nn
#pragma unroll
  for (int i = 0; i < 4; ++i)
#pragma unroll
    for (int j = 0; j < 4; ++j) acc[i][j] = (f4v){0.f, 0.f, 0.f, 0.f};
  float ksum[4] = {0.f, 0.f, 0.f, 0.f};

  const size_t bhbase = (size_t)b * LL * HH * DD + (size_t)h * DD;

  for (int it = 0; it < 8; ++it) {
    const int lt0 = l0 + it * 64;

    // ---- wave-private v staging: full 64x64 tile per wave (16 f4v/lane) ----
#pragma unroll
    for (int t = 0; t < 16; ++t) {
      int linear = t * 256 + lane * 4;  // 0..4092
      int row = linear >> 6, col = linear & 63;
      f4v vv = *(const f4v*)(vin + bhbase + (size_t)(lt0 + row) * (HH * DD) + col);
      bf4v x;
#pragma unroll
      for (int j = 0; j < 4; ++j) x[j] = f2bf(vv[j]);
      *(bf4v*)&vtw[row * 68 + col] = x;
    }

    // ---- GEMM1 (A = k direct from global) ; phi ; ksum ; kft write ----
#pragma unroll
    for (int lt = 0; lt < 4; ++lt) {
      const float* krow = kin + bhbase + (size_t)(lt0 + lt * 16 + nn) * (HH * DD) + qd * 8;
      f4v ka0 = *(const f4v*)(krow);
      f4v ka1 = *(const f4v*)(krow + 4);
      f4v ka2 = *(const f4v*)(krow + 32);
      f4v ka3 = *(const f4v*)(krow + 36);
      bf8v a0, a1;
#pragma unroll
      for (int j = 0; j < 4; ++j) {
        a0[j] = f2bf(ka0[j]); a0[j + 4] = f2bf(ka1[j]);
        a1[j] = f2bf(ka2[j]); a1[j + 4] = f2bf(ka3[j]);
      }
#pragma unroll
      for (int mt = 0; mt < 4; ++mt) {
        f4v cc = (f4v){0.f, 0.f, 0.f, 0.f};
        cc = MFMA16(a0, pf[mt][0], cc);
        cc = MFMA16(a1, pf[mt][1], cc);
        // lane holds rows l = lt*16+4qd+r, col m(band) = mt*16+nn
        bf4v pk;
#pragma unroll
        for (int r = 0; r < 4; ++r) {
          float ph = fmaxf(cc[r], 0.f) + 1e-3f;
          ksum[mt] += ph;
          pk[r] = f2bf(ph);
        }
        *(bf4v*)&kftw[(mt * 16 + nn) * 72 + lt * 16 + qd * 4] = pk;
      }
    }

    // ---- GEMM2: acc += kft(own band) . v(own tile) ----
#pragma unroll
    for (int c = 0; c < 2; ++c) {
      bf8v af[4];
#pragma unroll
      for (int mt = 0; mt < 4; ++mt)
        af[mt] = *(const bf8v*)&kftw[(mt * 16 + nn) * 72 + c * 32 + qd * 8];
#pragma unroll
      for (int et = 0; et < 4; ++et) {
        bf8v bv;
#pragma unroll
        for (int j = 0; j < 8; ++j) bv[j] = vtw[(c * 32 + qd * 8 + j) * 68 + et * 16 + nn];
#pragma unroll
        for (int mt = 0; mt < 4; ++mt) acc[mt][et] = MFMA16(af[mt], bv, acc[mt][et]);
      }
    }
  }

  // ---- epilogue: atomic-accumulate KVt[bh][e][m] and Ksum[bh][m] ----
  float* kvb = ws + (size_t)bh * (64 * 256);
#pragma unroll
  for (int mt = 0; mt < 4; ++mt)
#pragma unroll
    for (int et = 0; et < 4; ++et)
#pragma unroll
      for (int r = 0; r < 4; ++r) {
        int m = 64 * wave + mt * 16 + 4 * qd + r;
        int e = et * 16 + nn;
        atomicAdd(&kvb[e * 256 + m], acc[mt][et][r]);
      }
#pragma unroll
  for (int mt = 0; mt < 4; ++mt) {
    float s = ksum[mt];
    s += __shfl_xor(s, 16, 64);
    s += __shfl_xor(s, 32, 64);
    if (lane < 16) atomicAdd(&ws[KSUM_OFF + bh * 256 + 64 * wave + mt * 16 + lane], s);
  }
}

// ---------------------------------------------------------------------------
// Kernel 3: out = (phi(q) @ KV) / (phi(q) . (Ksum+1e-6)).
// grid (16, 64), 256 thr, 4 iters of 64 rows. 2 barriers/iter (qf exchange).
// q B-frags direct global; den via extra all-equal-columns MFMA B-operand.
// ---------------------------------------------------------------------------
__global__ __launch_bounds__(256, 3)
void k3_out(const float* __restrict__ qin, const float* __restrict__ pin,
            const float* __restrict__ ws, float* __restrict__ out) {
  __shared__ __bf16 qf[64 * 264];  // phi(q) [l][m], cross-wave

  const int tid = threadIdx.x;
  const int wave = tid >> 6;
  const int lane = tid & 63;
  const int qd = lane >> 4;
  const int nn = lane & 15;
  const int bh = blockIdx.y;
  const int b = bh >> 4, h = bh & 15;
  const int l0 = blockIdx.x * 256;

  // P fragments (A-op of GEMM3'): rows m = 64w+mt*16+nn.
  bf8v pf[4][2];
#pragma unroll
  for (int mt = 0; mt < 4; ++mt) {
    const float* pr = pin + (size_t)(64 * wave + mt * 16 + nn) * DD;
#pragma unroll
    for (int c = 0; c < 2; ++c) {
      bf8v t;
#pragma unroll
      for (int j = 0; j < 8; ++j) t[j] = f2bf(pr[c * 32 + qd * 8 + j] * SCALE);
      pf[mt][c] = t;
    }
  }

  // KV B-frags: e = 16*wave + nn, k m = c*32 + qd*8 + j.
  const float* kvb = ws + (size_t)bh * (64 * 256);
  bf8v kvf[8];
#pragma unroll
  for (int c = 0; c < 8; ++c) {
    const float* src = kvb + (size_t)(16 * wave + nn) * 256 + c * 32 + qd * 8;
    bf8v t;
#pragma unroll
    for (int j = 0; j < 8; ++j) t[j] = f2bf(src[j]);
    kvf[c] = t;
  }
  // den B-frags: every column n holds ksume[k] -> C col n all hold den[l].
  bf8v kvd[8];
#pragma unroll
  for (int c = 0; c < 8; ++c) {
    const float* src = ws + KSUM_OFF + bh * 256 + c * 32 + qd * 8;
    f4v s0 = *(const f4v*)src, s1 = *(const f4v*)(src + 4);
    bf8v t;
#pragma unroll
    for (int j = 0; j < 4; ++j) {
      t[j] = f2bf(s0[j] + 1e-6f);
      t[j + 4] = f2bf(s1[j] + 1e-6f);
    }
    kvd[c] = t;
  }

  const size_t bhbase = (size_t)b * LL * HH * DD + (size_t)h * DD;

  for (int it = 0; it < 4; ++it) {
    const int lt0 = l0 + it * 64;

    // ---- GEMM3': C[m][l] = P . q^T (q direct global) ; phi ; qf[l][m] ----
#pragma unroll
    for (int lt = 0; lt < 4; ++lt) {
      const float* qrow = qin + bhbase + (size_t)(lt0 + lt * 16 + nn) * (HH * DD) + qd * 8;
      f4v qa0 = *(const f4v*)(qrow);
      f4v qa1 = *(const f4v*)(qrow + 4);
      f4v qa2 = *(const f4v*)(qrow + 32);
      f4v qa3 = *(const f4v*)(qrow + 36);
      bf8v b0, b1;
#pragma unroll
      for (int j = 0; j < 4; ++j) {
        b0[j] = f2bf(qa0[j]); b0[j + 4] = f2bf(qa1[j]);
        b1[j] = f2bf(qa2[j]); b1[j + 4] = f2bf(qa3[j]);
      }
#pragma unroll
      for (int mt = 0; mt < 4; ++mt) {
        f4v cc = (f4v){0.f, 0.f, 0.f, 0.f};
        cc = MFMA16(pf[mt][0], b0, cc);
        cc = MFMA16(pf[mt][1], b1, cc);
        // lane holds rows m = 64w+mt*16+4qd+r, col l = lt*16+nn
        bf4v pk;
#pragma unroll
        for (int r = 0; r < 4; ++r) pk[r] = f2bf(fmaxf(cc[r], 0.f) + 1e-3f);
        *(bf4v*)&qf[(lt * 16 + nn) * 264 + 64 * wave + mt * 16 + 4 * qd] = pk;
      }
    }
    __syncthreads();

    // ---- GEMM4 (+ den column): out rows l = lt*16+4qd+r, col e = 16w+nn ----
#pragma unroll
    for (int lt = 0; lt < 4; ++lt) {
      f4v co = (f4v){0.f, 0.f, 0.f, 0.f};
      f4v cd = (f4v){0.f, 0.f, 0.f, 0.f};
#pragma unroll
      for (int c = 0; c < 8; ++c) {
        bf8v af = *(const bf8v*)&qf[(lt * 16 + nn) * 264 + c * 32 + qd * 8];
        co = MFMA16(af, kvf[c], co);
        cd = MFMA16(af, kvd[c], cd);
      }
#pragma unroll
      for (int r = 0; r < 4; ++r) {
        int lrel = lt * 16 + 4 * qd + r;
        int labs = lt0 + lrel;
        out[((size_t)((size_t)b * LL + labs) * HH + h) * EE + 16 * wave + nn] =
            co[r] / cd[r];
      }
    }
    __syncthreads();
  }
}

extern "C" void kernel_launch(void* const* d_in, const int* in_sizes, int n_in,
                              void* d_out, int out_size, void* d_ws, size_t ws_size,
                              hipStream_t stream) {
  (void)in_sizes; (void)n_in; (void)out_size;
  const float* q = (const float*)d_in[0];
  const float* k = (const float*)d_in[1];
  const float* v = (const float*)d_in[2];
  const float* p = (const float*)d_in[3];
  float* ws = (float*)d_ws;
  float* out = (float*)d_out;

  if (ws_size < WS_ZERO_BYTES) return;

  hipMemsetAsync(d_ws, 0, WS_ZERO_BYTES, stream);
  dim3 blk(256);
  k1_kv<<<dim3(8, 64), blk, 0, stream>>>(k, v, p, ws);
  k3_out<<<dim3(16, 64), blk, 0, stream>>>(q, p, ws, out);
}